// Round 24
// baseline (166.963 us; speedup 1.0000x reference)
//
#include <hip/hip_runtime.h>

// GIN 2-layer, eval. Transform-then-aggregate (both aggregations 32-wide):
//   y1 = x@W1a  (MFMA bf16, stored bf16)
//   pre1 = y1 + gather(y1) + b1a ; t1 = relu(bn1(pre1)) ; h1 = relu(t1@W1b+b1b)  (h1 bf16)
//   s1  = h1 + gather(h1)        ; t2 = relu(bn2(s1@W2a+b2a))  (t2 bf16 in ws)
//   out = t2@W2b + b2b   -> d_out
// Front-end FUSED (stage + gemm in one dispatch, data-independent). EPB=2048
// keeps the union LDS at 32.8 KB -> 4 blocks/CU (R22's 52.8 KB capped at 2).
// Then refill -> layer1 -> layer2a -> final.

#define BN_EPS 1e-5f
#define BKT 128
#define BKT_SH 7
#define EPB 2048            // edges per stage block (32.8 KB LDS)
#define MAXB 800            // max dst-buckets supported (N <= 102400)
#define LDS_E 2560          // refill LDS edge buffer = max cap

typedef __attribute__((ext_vector_type(8))) short bf16x8;
typedef __attribute__((ext_vector_type(4))) float f32x4v;

__device__ __forceinline__ unsigned short f2bf(float f) {
    unsigned u = __float_as_uint(f);
    return (unsigned short)((u + 0x7FFFu + ((u >> 16) & 1u)) >> 16);   // RNE
}
__device__ __forceinline__ float bflo(unsigned u) { return __uint_as_float(u << 16); }
__device__ __forceinline__ float bfhi(unsigned u) { return __uint_as_float(u & 0xFFFF0000u); }

__device__ __forceinline__ void gacc8(uint4 v, float w, float* acc) {
    acc[0] += bflo(v.x) * w; acc[1] += bfhi(v.x) * w;
    acc[2] += bflo(v.y) * w; acc[3] += bfhi(v.y) * w;
    acc[4] += bflo(v.z) * w; acc[5] += bfhi(v.z) * w;
    acc[6] += bflo(v.w) * w; acc[7] += bfhi(v.w) * w;
}

// 4-deep pipelined gather over CSR segment [e, end): acc[0..7] += w * tab[src][c0..c0+7]
__device__ __forceinline__ void gather_seg8(const unsigned short* __restrict__ tab,
                                            const int2* __restrict__ epack,
                                            int e, int end, int c0, float* acc) {
    long long q0 = 0, q1 = 0, q2 = 0, q3 = 0;
    if (e + 4 <= end) {
        q0 = __builtin_nontemporal_load((const long long*)&epack[e + 0]);
        q1 = __builtin_nontemporal_load((const long long*)&epack[e + 1]);
        q2 = __builtin_nontemporal_load((const long long*)&epack[e + 2]);
        q3 = __builtin_nontemporal_load((const long long*)&epack[e + 3]);
    }
    for (; e + 8 <= end; e += 4) {
        int s0 = (int)q0, s1 = (int)q1, s2 = (int)q2, s3 = (int)q3;
        float w0 = __int_as_float((int)(q0 >> 32));
        float w1 = __int_as_float((int)(q1 >> 32));
        float w2 = __int_as_float((int)(q2 >> 32));
        float w3 = __int_as_float((int)(q3 >> 32));
        uint4 v0 = *(const uint4*)&tab[(size_t)s0 * 32 + c0];
        uint4 v1 = *(const uint4*)&tab[(size_t)s1 * 32 + c0];
        uint4 v2 = *(const uint4*)&tab[(size_t)s2 * 32 + c0];
        uint4 v3 = *(const uint4*)&tab[(size_t)s3 * 32 + c0];
        q0 = __builtin_nontemporal_load((const long long*)&epack[e + 4]);
        q1 = __builtin_nontemporal_load((const long long*)&epack[e + 5]);
        q2 = __builtin_nontemporal_load((const long long*)&epack[e + 6]);
        q3 = __builtin_nontemporal_load((const long long*)&epack[e + 7]);
        gacc8(v0, w0, acc); gacc8(v1, w1, acc);
        gacc8(v2, w2, acc); gacc8(v3, w3, acc);
    }
    if (e + 4 <= end) {
        int s0 = (int)q0, s1 = (int)q1, s2 = (int)q2, s3 = (int)q3;
        float w0 = __int_as_float((int)(q0 >> 32));
        float w1 = __int_as_float((int)(q1 >> 32));
        float w2 = __int_as_float((int)(q2 >> 32));
        float w3 = __int_as_float((int)(q3 >> 32));
        uint4 v0 = *(const uint4*)&tab[(size_t)s0 * 32 + c0];
        uint4 v1 = *(const uint4*)&tab[(size_t)s1 * 32 + c0];
        uint4 v2 = *(const uint4*)&tab[(size_t)s2 * 32 + c0];
        uint4 v3 = *(const uint4*)&tab[(size_t)s3 * 32 + c0];
        gacc8(v0, w0, acc); gacc8(v1, w1, acc);
        gacc8(v2, w2, acc); gacc8(v3, w3, acc);
        e += 4;
    }
    for (; e < end; ++e) {
        long long q = __builtin_nontemporal_load((const long long*)&epack[e]);
        int sn = (int)q;
        float w = __int_as_float((int)(q >> 32));
        uint4 v = *(const uint4*)&tab[(size_t)sn * 32 + c0];
        gacc8(v, w, acc);
    }
}

// ---- K1 (fused): blocks [0, G_STAGE) = stage counting sort; rest = MFMA gemm1 ----
union SMem {
    struct {
        int hist[MAXB], base_[MAXB], curs[MAXB], gbase[MAXB];   // 12.8 KB
        int2 data[EPB];                                         // 16 KB
        unsigned short bslot[EPB];                              // 4 KB
    } st;                                   // 32.8 KB
    struct { unsigned short wbT[32][136]; } gm;   // 8.7 KB
};

__global__ __launch_bounds__(512) void gs_kernel(const float* __restrict__ x,
                                                 const float* __restrict__ W,
                                                 unsigned short* __restrict__ y1b,
                                                 const int* __restrict__ ei,
                                                 const float* __restrict__ ew,
                                                 int* __restrict__ gcur,
                                                 int2* __restrict__ staged,
                                                 int N, int E, int cap, int NBUCK,
                                                 int G_STAGE) {
    __shared__ SMem sm;
    int t = threadIdx.x;
    if ((int)blockIdx.x < G_STAGE) {
        // ---------------- STAGE branch ----------------
        int e0 = blockIdx.x * EPB;
        int cnt = min(EPB, E - e0);
        for (int i = t; i < MAXB; i += 512) sm.st.hist[i] = 0;
        __syncthreads();
        for (int i = t; i < cnt; i += 512) {
            int d = ei[(size_t)E + e0 + i];
            atomicAdd(&sm.st.hist[d >> BKT_SH], 1);
        }
        __syncthreads();
        int lo = t * 2;
        int v0 = (lo + 0 < MAXB) ? sm.st.hist[lo + 0] : 0;
        int v1 = (lo + 1 < MAXB) ? sm.st.hist[lo + 1] : 0;
        int s = v0 + v1;
        sm.st.gbase[t] = s;
        __syncthreads();
        for (int off = 1; off < 512; off <<= 1) {
            int y = (t >= off) ? sm.st.gbase[t - off] : 0;
            __syncthreads();
            sm.st.gbase[t] += y;
            __syncthreads();
        }
        int excl = sm.st.gbase[t] - s;
        if (lo + 0 < MAXB) { sm.st.base_[lo + 0] = excl; sm.st.curs[lo + 0] = excl; }
        excl += v0;
        if (lo + 1 < MAXB) { sm.st.base_[lo + 1] = excl; sm.st.curs[lo + 1] = excl; }
        __syncthreads();
        for (int i = t; i < cnt; i += 512) {
            int sn = ei[e0 + i];
            int d  = ei[(size_t)E + e0 + i];
            float w = ew[e0 + i];
            int b = d >> BKT_SH, dl = d & (BKT - 1);
            int pos = atomicAdd(&sm.st.curs[b], 1);
            sm.st.data[pos]  = make_int2((dl << 20) | sn, __float_as_int(w));
            sm.st.bslot[pos] = (unsigned short)b;
        }
        __syncthreads();
        for (int b = t; b < NBUCK; b += 512) {
            int c = sm.st.hist[b];
            sm.st.gbase[b] = c ? atomicAdd(&gcur[b * 16], c) : 0;
        }
        __syncthreads();
        for (int i = t; i < cnt; i += 512) {
            int b  = sm.st.bslot[i];
            int gp = sm.st.gbase[b] + (i - sm.st.base_[b]);
            if (gp < cap) staged[(size_t)b * cap + gp] = sm.st.data[i];
        }
    } else {
        // ---------------- GEMM branch (128 rows/block, 8 MFMA waves) ----------------
        int gb = (int)blockIdx.x - G_STAGE;
        for (int i = t; i < 4096; i += 512) {
            int k = i >> 5, c = i & 31;
            sm.gm.wbT[c][k] = f2bf(W[i]);
        }
        __syncthreads();
        int wid = t >> 6, lane = t & 63;
        int lr = lane & 15, lg = lane >> 4;
        int arow = gb * 128 + wid * 16 + lr;
        int xr = min(arow, N - 1);
        bf16x8 bfr[4][2];
        #pragma unroll
        for (int s = 0; s < 4; ++s) {
            int kb = s * 32 + lg * 8;
            bfr[s][0] = *(const bf16x8*)&sm.gm.wbT[lr][kb];
            bfr[s][1] = *(const bf16x8*)&sm.gm.wbT[16 + lr][kb];
        }
        f32x4v acc0 = {0.f, 0.f, 0.f, 0.f};
        f32x4v acc1 = {0.f, 0.f, 0.f, 0.f};
        #pragma unroll
        for (int s = 0; s < 4; ++s) {
            const float* xp = &x[(size_t)xr * 128 + s * 32 + lg * 8];
            float4 xa = *(const float4*)xp;
            float4 xb = *(const float4*)(xp + 4);
            bf16x8 af;
            af[0] = (short)f2bf(xa.x); af[1] = (short)f2bf(xa.y);
            af[2] = (short)f2bf(xa.z); af[3] = (short)f2bf(xa.w);
            af[4] = (short)f2bf(xb.x); af[5] = (short)f2bf(xb.y);
            af[6] = (short)f2bf(xb.z); af[7] = (short)f2bf(xb.w);
            acc0 = __builtin_amdgcn_mfma_f32_16x16x32_bf16(af, bfr[s][0], acc0, 0, 0, 0);
            acc1 = __builtin_amdgcn_mfma_f32_16x16x32_bf16(af, bfr[s][1], acc1, 0, 0, 0);
        }
        int rowbase = gb * 128 + wid * 16 + lg * 4;
        #pragma unroll
        for (int r = 0; r < 4; ++r) {
            int orow = rowbase + r;
            if (orow < N) {
                y1b[(size_t)orow * 32 + lr]      = f2bf(acc0[r]);
                y1b[(size_t)orow * 32 + 16 + lr] = f2bf(acc1[r]);
            }
        }
    }
}

// ------- K2: refill (single pass via LDS) -> epack at b*cap, row_se=int2(beg,end) -------
__global__ __launch_bounds__(256) void refill_kernel(const int2* __restrict__ staged,
                                                     const int* __restrict__ gcur,
                                                     int2* __restrict__ epack,
                                                     int2* __restrict__ row_se,
                                                     int N, int cap) {
    __shared__ int2 ebuf[LDS_E];
    __shared__ int hist[BKT];
    __shared__ int curs[BKT];
    int b = blockIdx.x, t = threadIdx.x;
    int cnt  = min(gcur[b * 16], cap);
    int base = b * cap;
    size_t e0 = (size_t)b * cap;
    if (t < BKT) hist[t] = 0;
    __syncthreads();
    for (int i = t; i < cnt; i += 256) {
        int2 p = staged[e0 + i];
        ebuf[i] = p;
        atomicAdd(&hist[p.x >> 20], 1);
    }
    __syncthreads();
    if (t < BKT) curs[t] = hist[t];
    __syncthreads();
    for (int off = 1; off < BKT; off <<= 1) {
        int y = (t < BKT && t >= off) ? curs[t - off] : 0;
        __syncthreads();
        if (t < BKT) curs[t] += y;
        __syncthreads();
    }
    if (t < BKT) {
        int excl = curs[t] - hist[t];
        int node = (b << BKT_SH) + t;
        if (node < N) row_se[node] = make_int2(base + excl, base + excl + hist[t]);
        curs[t] = excl;
    }
    __syncthreads();
    for (int i = t; i < cnt; i += 256) {
        int2 p = ebuf[i];
        int dl = p.x >> 20;
        int pos = base + atomicAdd(&curs[dl], 1);
        epack[pos] = make_int2(p.x & 0xFFFFF, p.y);
    }
}

// ------- K3: gather(y1b) + BN + ReLU + @W1b + ReLU -> h1b  (64 nodes/block, 4 lanes/node) -------
__global__ __launch_bounds__(256) void layer1_kernel(
    const unsigned short* __restrict__ y1b, const int2* __restrict__ row_se,
    const int2* __restrict__ epack,
    const float* __restrict__ b1a, const float* __restrict__ g1,
    const float* __restrict__ be1, const float* __restrict__ m1,
    const float* __restrict__ v1, const float* __restrict__ W1b,
    const float* __restrict__ b1b, unsigned short* __restrict__ h1b, int N) {
    __shared__ float w1b[1024];
    __shared__ float t1s[64][33];
    int t = threadIdx.x;
    for (int i = t; i < 1024; i += 256) w1b[i] = W1b[i];
    __syncthreads();                    // weights visible BEFORE variable gather
    int g = t >> 2, l = t & 3;
    int node = blockIdx.x * 64 + g;
    int c0 = l << 3;
    bool act = node < N;
    float acc[8] = {0.f, 0.f, 0.f, 0.f, 0.f, 0.f, 0.f, 0.f};
    if (act) {
        int2 se = row_se[node];
        uint4 sv = *(const uint4*)&y1b[(size_t)node * 32 + c0];   // hoisted self load
        gather_seg8(y1b, epack, se.x, se.y, c0, acc);
        gacc8(sv, 1.f, acc);                        // + self
        #pragma unroll
        for (int j = 0; j < 8; ++j) {
            int c = c0 + j;
            float scale = g1[c] * rsqrtf(v1[c] + BN_EPS);
            t1s[g][c] = fmaxf((acc[j] + b1a[c] - m1[c]) * scale + be1[c], 0.f);
        }
    }
    asm volatile("" ::: "memory");      // same-wave LDS producer/consumer: no barrier
    if (act) {
        float a[8];
        #pragma unroll
        for (int j = 0; j < 8; ++j) a[j] = b1b[c0 + j];
        #pragma unroll
        for (int k = 0; k < 32; ++k) {
            float tv = t1s[g][k];
            const float* wr = &w1b[k * 32 + c0];
            #pragma unroll
            for (int j = 0; j < 8; ++j) a[j] += tv * wr[j];
        }
        unsigned long long p0 = 0, p1 = 0;
        #pragma unroll
        for (int j = 0; j < 4; ++j)
            p0 |= (unsigned long long)f2bf(fmaxf(a[j], 0.f)) << (16 * j);
        #pragma unroll
        for (int j = 0; j < 4; ++j)
            p1 |= (unsigned long long)f2bf(fmaxf(a[4 + j], 0.f)) << (16 * j);
        __builtin_nontemporal_store(p0, (unsigned long long*)&h1b[(size_t)node * 32 + c0 + 0]);
        __builtin_nontemporal_store(p1, (unsigned long long*)&h1b[(size_t)node * 32 + c0 + 4]);
    }
}

// ------- K4: gather(h1b) -> s1 ; @W2a + BN + ReLU -> t2b  (64 nodes/block) -------
__global__ __launch_bounds__(256) void layer2a_kernel(
    const unsigned short* __restrict__ h1b, const int2* __restrict__ row_se,
    const int2* __restrict__ epack,
    const float* __restrict__ W2a, const float* __restrict__ b2a,
    const float* __restrict__ g2, const float* __restrict__ be2,
    const float* __restrict__ m2, const float* __restrict__ v2,
    unsigned short* __restrict__ t2b, int N) {
    __shared__ float w2a[2048];
    __shared__ float s1s[64][33];
    __shared__ float sc2s[64], sh2s[64];
    int t = threadIdx.x;
    for (int i = t; i < 2048; i += 256) w2a[i] = W2a[i];
    if (t < 64) {
        float sc = g2[t] * rsqrtf(v2[t] + BN_EPS);
        sc2s[t] = sc;
        sh2s[t] = (b2a[t] - m2[t]) * sc + be2[t];   // b2a folded into BN shift
    }
    __syncthreads();                    // weights visible BEFORE variable gather
    int g = t >> 2, l = t & 3;
    int node = blockIdx.x * 64 + g;
    int c0 = l << 3;
    bool act = node < N;
    float acc[8] = {0.f, 0.f, 0.f, 0.f, 0.f, 0.f, 0.f, 0.f};
    if (act) {
        int2 se = row_se[node];
        uint4 sv = *(const uint4*)&h1b[(size_t)node * 32 + c0];   // hoisted self load
        gather_seg8(h1b, epack, se.x, se.y, c0, acc);
        gacc8(sv, 1.f, acc);
        #pragma unroll
        for (int j = 0; j < 8; ++j) s1s[g][c0 + j] = acc[j];
    }
    asm volatile("" ::: "memory");      // same-wave LDS producer/consumer
    if (act) {
        int d0 = l << 4;                 // 16 output cols per lane
        float a[16];
        #pragma unroll
        for (int j = 0; j < 16; ++j) a[j] = 0.f;
        #pragma unroll
        for (int k = 0; k < 32; ++k) {
            float sv = s1s[g][k];
            const float* wr = &w2a[k * 64 + d0];
            #pragma unroll
            for (int j = 0; j < 16; ++j) a[j] += sv * wr[j];
        }
        unsigned long long pk[4] = {0, 0, 0, 0};
        #pragma unroll
        for (int j = 0; j < 16; ++j) {
            int c = d0 + j;
            float o = fmaxf(a[j] * sc2s[c] + sh2s[c], 0.f);
            pk[j >> 2] |= (unsigned long long)f2bf(o) << (16 * (j & 3));
        }
        #pragma unroll
        for (int q = 0; q < 4; ++q)
            __builtin_nontemporal_store(pk[q],
                (unsigned long long*)&t2b[(size_t)node * 64 + d0 + 4 * q]);
    }
}

// ------- K5: out = t2b@W2b + b2b  (32 nodes/block, 8 thr/node, 8 outs/thread) -------
__global__ __launch_bounds__(256) void final_kernel(const unsigned short* __restrict__ t2b,
                                                    const float* __restrict__ W2b,
                                                    const float* __restrict__ b2b,
                                                    float* __restrict__ out, int N) {
    __shared__ float w2b[4096];        // 16 KB
    __shared__ float t2s[32][68];
    int t = threadIdx.x;
    for (int i = t; i < 4096; i += 256) w2b[i] = W2b[i];
    int g = t >> 3, l = t & 7;
    int node = blockIdx.x * 32 + g;
    int c0 = l << 3;
    bool act = node < N;
    if (act) {
        uint4 v = *(const uint4*)&t2b[(size_t)node * 64 + c0];
        t2s[g][c0 + 0] = bflo(v.x); t2s[g][c0 + 1] = bfhi(v.x);
        t2s[g][c0 + 2] = bflo(v.y); t2s[g][c0 + 3] = bfhi(v.y);
        t2s[g][c0 + 4] = bflo(v.z); t2s[g][c0 + 5] = bfhi(v.z);
        t2s[g][c0 + 6] = bflo(v.w); t2s[g][c0 + 7] = bfhi(v.w);
    }
    __syncthreads();
    if (act) {
        float a[8];
        #pragma unroll
        for (int j = 0; j < 8; ++j) a[j] = b2b[c0 + j];
        #pragma unroll 8
        for (int k = 0; k < 64; ++k) {
            float tv = t2s[g][k];
            const float* wr = &w2b[k * 64 + c0];
            float4 w0 = *(const float4*)wr;
            float4 w1 = *(const float4*)(wr + 4);
            a[0] += tv * w0.x; a[1] += tv * w0.y; a[2] += tv * w0.z; a[3] += tv * w0.w;
            a[4] += tv * w1.x; a[5] += tv * w1.y; a[6] += tv * w1.z; a[7] += tv * w1.w;
        }
        *(float4*)&out[(size_t)node * 64 + c0 + 0] = *(float4*)&a[0];
        *(float4*)&out[(size_t)node * 64 + c0 + 4] = *(float4*)&a[4];
    }
}

extern "C" void kernel_launch(void* const* d_in, const int* in_sizes, int n_in,
                              void* d_out, int out_size, void* d_ws, size_t ws_size,
                              hipStream_t stream) {
    const float* x   = (const float*)d_in[0];
    const float* ew  = (const float*)d_in[1];
    const float* W1a = (const float*)d_in[2];
    const float* b1a = (const float*)d_in[3];
    const float* g1  = (const float*)d_in[4];
    const float* be1 = (const float*)d_in[5];
    const float* m1  = (const float*)d_in[6];
    const float* v1  = (const float*)d_in[7];
    const float* W1b = (const float*)d_in[8];
    const float* b1b = (const float*)d_in[9];
    const float* W2a = (const float*)d_in[10];
    const float* b2a = (const float*)d_in[11];
    const float* g2  = (const float*)d_in[12];
    const float* be2 = (const float*)d_in[13];
    const float* m2  = (const float*)d_in[14];
    const float* v2  = (const float*)d_in[15];
    const float* W2b = (const float*)d_in[16];
    const float* b2b = (const float*)d_in[17];
    const int*   ei  = (const int*)d_in[18];

    const int N = in_sizes[0] / 128;
    const int E = in_sizes[1];
    const int NBUCK = (N + BKT - 1) >> BKT_SH;   // 782 for N=100000 (<= MAXB)
    const int NCUR  = NBUCK * 16;
    const int G_STAGE = (E + EPB - 1) / EPB;     // 782
    const int G_GEMM  = (N + 127) / 128;         // 782

    // ws layout: y1b | row_se | gcur | epack | staged
    // h1b aliases staged[0..N*32); t2b aliases staged[N*32..) — staged dead
    // after refill; h1b reads and t2b writes are disjoint ranges.
    unsigned short* y1b = (unsigned short*)d_ws;              // N*32 bf16
    int2*  row_se  = (int2*)(y1b + (size_t)N * 32);           // N int2
    int*   gcur    = (int*)(row_se + N);                      // NCUR (64B pad)
    int2*  epack   = (int2*)(gcur + NCUR + 16);               // NBUCK*cap
    size_t fixed_bytes = (char*)epack - (char*)d_ws;
    size_t avail = (ws_size > fixed_bytes) ? (ws_size - fixed_bytes) : 0;
    int cap = (int)((avail / (2 * sizeof(int2))) / NBUCK);
    cap &= ~63;
    if (cap > LDS_E) cap = LDS_E;   // mean bucket load ~2048, max ~2300
    int2* staged = epack + (size_t)NBUCK * cap;
    unsigned short* h1b = (unsigned short*)staged;            // N*32 bf16 (alias)
    unsigned short* t2b = h1b + (size_t)N * 32;               // N*64 bf16 (alias)

    hipMemsetAsync(gcur, 0, (size_t)NCUR * sizeof(int), stream);
    gs_kernel<<<G_STAGE + G_GEMM, 512, 0, stream>>>(x, W1a, y1b, ei, ew, gcur, staged,
                                                    N, E, cap, NBUCK, G_STAGE);
    refill_kernel<<<NBUCK, 256, 0, stream>>>(staged, gcur, epack, row_se, N, cap);
    layer1_kernel<<<(N + 63) / 64, 256, 0, stream>>>(y1b, row_se, epack,
                                                     b1a, g1, be1, m1, v1, W1b, b1b, h1b, N);
    layer2a_kernel<<<(N + 63) / 64, 256, 0, stream>>>(h1b, row_se, epack,
                                                      W2a, b2a, g2, be2, m2, v2, t2b, N);
    final_kernel<<<(N + 31) / 32, 256, 0, stream>>>(t2b, W2b, b2b, (float*)d_out, N);
}

// Round 25
// 149.329 us; speedup vs baseline: 1.1181x; 1.1181x over previous
//
#include <hip/hip_runtime.h>

// GIN 2-layer, eval. Transform-then-aggregate (both aggregations 32-wide):
//   y1 = x@W1a  (MFMA bf16, stored bf16)
//   pre1 = y1 + gather(y1) + b1a ; t1 = relu(bn1(pre1)) ; h1 = relu(t1@W1b+b1b)  (h1 bf16)
//   s1  = h1 + gather(h1)        ; t2 = relu(bn2(s1@W2a+b2a))  (t2 bf16 in ws)
//   out = t2@W2b + b2b   -> d_out
// Front-end FUSED: one dispatch runs stage blocks (512-thr counting sort,
// EPB=4096 — the write-amplification sweet spot; EPB=2048 regressed) AND
// gemm blocks (MFMA, 128 rows/block). Then refill -> layer1 -> layer2a -> final.

#define BN_EPS 1e-5f
#define BKT 128
#define BKT_SH 7
#define EPB 4096            // edges per stage block
#define MAXB 800            // max dst-buckets supported (N <= 102400)
#define LDS_E 2560          // refill LDS edge buffer = max cap

typedef __attribute__((ext_vector_type(8))) short bf16x8;
typedef __attribute__((ext_vector_type(4))) float f32x4v;

__device__ __forceinline__ unsigned short f2bf(float f) {
    unsigned u = __float_as_uint(f);
    return (unsigned short)((u + 0x7FFFu + ((u >> 16) & 1u)) >> 16);   // RNE
}
__device__ __forceinline__ float bflo(unsigned u) { return __uint_as_float(u << 16); }
__device__ __forceinline__ float bfhi(unsigned u) { return __uint_as_float(u & 0xFFFF0000u); }

__device__ __forceinline__ void gacc8(uint4 v, float w, float* acc) {
    acc[0] += bflo(v.x) * w; acc[1] += bfhi(v.x) * w;
    acc[2] += bflo(v.y) * w; acc[3] += bfhi(v.y) * w;
    acc[4] += bflo(v.z) * w; acc[5] += bfhi(v.z) * w;
    acc[6] += bflo(v.w) * w; acc[7] += bfhi(v.w) * w;
}

// 4-deep pipelined gather over CSR segment [e, end): acc[0..7] += w * tab[src][c0..c0+7]
__device__ __forceinline__ void gather_seg8(const unsigned short* __restrict__ tab,
                                            const int2* __restrict__ epack,
                                            int e, int end, int c0, float* acc) {
    long long q0 = 0, q1 = 0, q2 = 0, q3 = 0;
    if (e + 4 <= end) {
        q0 = __builtin_nontemporal_load((const long long*)&epack[e + 0]);
        q1 = __builtin_nontemporal_load((const long long*)&epack[e + 1]);
        q2 = __builtin_nontemporal_load((const long long*)&epack[e + 2]);
        q3 = __builtin_nontemporal_load((const long long*)&epack[e + 3]);
    }
    for (; e + 8 <= end; e += 4) {
        int s0 = (int)q0, s1 = (int)q1, s2 = (int)q2, s3 = (int)q3;
        float w0 = __int_as_float((int)(q0 >> 32));
        float w1 = __int_as_float((int)(q1 >> 32));
        float w2 = __int_as_float((int)(q2 >> 32));
        float w3 = __int_as_float((int)(q3 >> 32));
        uint4 v0 = *(const uint4*)&tab[(size_t)s0 * 32 + c0];
        uint4 v1 = *(const uint4*)&tab[(size_t)s1 * 32 + c0];
        uint4 v2 = *(const uint4*)&tab[(size_t)s2 * 32 + c0];
        uint4 v3 = *(const uint4*)&tab[(size_t)s3 * 32 + c0];
        q0 = __builtin_nontemporal_load((const long long*)&epack[e + 4]);
        q1 = __builtin_nontemporal_load((const long long*)&epack[e + 5]);
        q2 = __builtin_nontemporal_load((const long long*)&epack[e + 6]);
        q3 = __builtin_nontemporal_load((const long long*)&epack[e + 7]);
        gacc8(v0, w0, acc); gacc8(v1, w1, acc);
        gacc8(v2, w2, acc); gacc8(v3, w3, acc);
    }
    if (e + 4 <= end) {
        int s0 = (int)q0, s1 = (int)q1, s2 = (int)q2, s3 = (int)q3;
        float w0 = __int_as_float((int)(q0 >> 32));
        float w1 = __int_as_float((int)(q1 >> 32));
        float w2 = __int_as_float((int)(q2 >> 32));
        float w3 = __int_as_float((int)(q3 >> 32));
        uint4 v0 = *(const uint4*)&tab[(size_t)s0 * 32 + c0];
        uint4 v1 = *(const uint4*)&tab[(size_t)s1 * 32 + c0];
        uint4 v2 = *(const uint4*)&tab[(size_t)s2 * 32 + c0];
        uint4 v3 = *(const uint4*)&tab[(size_t)s3 * 32 + c0];
        gacc8(v0, w0, acc); gacc8(v1, w1, acc);
        gacc8(v2, w2, acc); gacc8(v3, w3, acc);
        e += 4;
    }
    for (; e < end; ++e) {
        long long q = __builtin_nontemporal_load((const long long*)&epack[e]);
        int sn = (int)q;
        float w = __int_as_float((int)(q >> 32));
        uint4 v = *(const uint4*)&tab[(size_t)sn * 32 + c0];
        gacc8(v, w, acc);
    }
}

// ---- K1 (fused): blocks [0, G_STAGE) = stage counting sort; rest = MFMA gemm1 ----
union SMem {
    struct {
        int hist[MAXB], base_[MAXB], curs[MAXB], gbase[MAXB];
        int2 data[EPB];
        unsigned short bslot[EPB];
    } st;                                   // 52.8 KB
    struct { unsigned short wbT[32][136]; } gm;   // 8.7 KB
};

__global__ __launch_bounds__(512) void gs_kernel(const float* __restrict__ x,
                                                 const float* __restrict__ W,
                                                 unsigned short* __restrict__ y1b,
                                                 const int* __restrict__ ei,
                                                 const float* __restrict__ ew,
                                                 int* __restrict__ gcur,
                                                 int2* __restrict__ staged,
                                                 int N, int E, int cap, int NBUCK,
                                                 int G_STAGE) {
    __shared__ SMem sm;
    int t = threadIdx.x;
    if ((int)blockIdx.x < G_STAGE) {
        // ---------------- STAGE branch ----------------
        int e0 = blockIdx.x * EPB;
        int cnt = min(EPB, E - e0);
        for (int i = t; i < MAXB; i += 512) sm.st.hist[i] = 0;
        __syncthreads();
        for (int i = t; i < cnt; i += 512) {
            int d = ei[(size_t)E + e0 + i];
            atomicAdd(&sm.st.hist[d >> BKT_SH], 1);
        }
        __syncthreads();
        int lo = t * 2;
        int v0 = (lo + 0 < MAXB) ? sm.st.hist[lo + 0] : 0;
        int v1 = (lo + 1 < MAXB) ? sm.st.hist[lo + 1] : 0;
        int s = v0 + v1;
        sm.st.gbase[t] = s;
        __syncthreads();
        for (int off = 1; off < 512; off <<= 1) {
            int y = (t >= off) ? sm.st.gbase[t - off] : 0;
            __syncthreads();
            sm.st.gbase[t] += y;
            __syncthreads();
        }
        int excl = sm.st.gbase[t] - s;
        if (lo + 0 < MAXB) { sm.st.base_[lo + 0] = excl; sm.st.curs[lo + 0] = excl; }
        excl += v0;
        if (lo + 1 < MAXB) { sm.st.base_[lo + 1] = excl; sm.st.curs[lo + 1] = excl; }
        __syncthreads();
        for (int i = t; i < cnt; i += 512) {
            int sn = ei[e0 + i];
            int d  = ei[(size_t)E + e0 + i];
            float w = ew[e0 + i];
            int b = d >> BKT_SH, dl = d & (BKT - 1);
            int pos = atomicAdd(&sm.st.curs[b], 1);
            sm.st.data[pos]  = make_int2((dl << 20) | sn, __float_as_int(w));
            sm.st.bslot[pos] = (unsigned short)b;
        }
        __syncthreads();
        for (int b = t; b < NBUCK; b += 512) {
            int c = sm.st.hist[b];
            sm.st.gbase[b] = c ? atomicAdd(&gcur[b * 16], c) : 0;
        }
        __syncthreads();
        for (int i = t; i < cnt; i += 512) {
            int b  = sm.st.bslot[i];
            int gp = sm.st.gbase[b] + (i - sm.st.base_[b]);
            if (gp < cap) staged[(size_t)b * cap + gp] = sm.st.data[i];
        }
    } else {
        // ---------------- GEMM branch (128 rows/block, 8 MFMA waves) ----------------
        int gb = (int)blockIdx.x - G_STAGE;
        for (int i = t; i < 4096; i += 512) {
            int k = i >> 5, c = i & 31;
            sm.gm.wbT[c][k] = f2bf(W[i]);
        }
        __syncthreads();
        int wid = t >> 6, lane = t & 63;
        int lr = lane & 15, lg = lane >> 4;
        int arow = gb * 128 + wid * 16 + lr;
        int xr = min(arow, N - 1);
        bf16x8 bfr[4][2];
        #pragma unroll
        for (int s = 0; s < 4; ++s) {
            int kb = s * 32 + lg * 8;
            bfr[s][0] = *(const bf16x8*)&sm.gm.wbT[lr][kb];
            bfr[s][1] = *(const bf16x8*)&sm.gm.wbT[16 + lr][kb];
        }
        f32x4v acc0 = {0.f, 0.f, 0.f, 0.f};
        f32x4v acc1 = {0.f, 0.f, 0.f, 0.f};
        #pragma unroll
        for (int s = 0; s < 4; ++s) {
            const float* xp = &x[(size_t)xr * 128 + s * 32 + lg * 8];
            float4 xa = *(const float4*)xp;
            float4 xb = *(const float4*)(xp + 4);
            bf16x8 af;
            af[0] = (short)f2bf(xa.x); af[1] = (short)f2bf(xa.y);
            af[2] = (short)f2bf(xa.z); af[3] = (short)f2bf(xa.w);
            af[4] = (short)f2bf(xb.x); af[5] = (short)f2bf(xb.y);
            af[6] = (short)f2bf(xb.z); af[7] = (short)f2bf(xb.w);
            acc0 = __builtin_amdgcn_mfma_f32_16x16x32_bf16(af, bfr[s][0], acc0, 0, 0, 0);
            acc1 = __builtin_amdgcn_mfma_f32_16x16x32_bf16(af, bfr[s][1], acc1, 0, 0, 0);
        }
        int rowbase = gb * 128 + wid * 16 + lg * 4;
        #pragma unroll
        for (int r = 0; r < 4; ++r) {
            int orow = rowbase + r;
            if (orow < N) {
                y1b[(size_t)orow * 32 + lr]      = f2bf(acc0[r]);
                y1b[(size_t)orow * 32 + 16 + lr] = f2bf(acc1[r]);
            }
        }
    }
}

// ------- K2: refill (single pass via LDS) -> epack at b*cap, row_se=int2(beg,end) -------
__global__ __launch_bounds__(256) void refill_kernel(const int2* __restrict__ staged,
                                                     const int* __restrict__ gcur,
                                                     int2* __restrict__ epack,
                                                     int2* __restrict__ row_se,
                                                     int N, int cap) {
    __shared__ int2 ebuf[LDS_E];
    __shared__ int hist[BKT];
    __shared__ int curs[BKT];
    int b = blockIdx.x, t = threadIdx.x;
    int cnt  = min(gcur[b * 16], cap);
    int base = b * cap;
    size_t e0 = (size_t)b * cap;
    if (t < BKT) hist[t] = 0;
    __syncthreads();
    for (int i = t; i < cnt; i += 256) {
        int2 p = staged[e0 + i];
        ebuf[i] = p;
        atomicAdd(&hist[p.x >> 20], 1);
    }
    __syncthreads();
    if (t < BKT) curs[t] = hist[t];
    __syncthreads();
    for (int off = 1; off < BKT; off <<= 1) {
        int y = (t < BKT && t >= off) ? curs[t - off] : 0;
        __syncthreads();
        if (t < BKT) curs[t] += y;
        __syncthreads();
    }
    if (t < BKT) {
        int excl = curs[t] - hist[t];
        int node = (b << BKT_SH) + t;
        if (node < N) row_se[node] = make_int2(base + excl, base + excl + hist[t]);
        curs[t] = excl;
    }
    __syncthreads();
    for (int i = t; i < cnt; i += 256) {
        int2 p = ebuf[i];
        int dl = p.x >> 20;
        int pos = base + atomicAdd(&curs[dl], 1);
        epack[pos] = make_int2(p.x & 0xFFFFF, p.y);
    }
}

// ------- K3: gather(y1b) + BN + ReLU + @W1b + ReLU -> h1b  (64 nodes/block, 4 lanes/node) -------
__global__ __launch_bounds__(256) void layer1_kernel(
    const unsigned short* __restrict__ y1b, const int2* __restrict__ row_se,
    const int2* __restrict__ epack,
    const float* __restrict__ b1a, const float* __restrict__ g1,
    const float* __restrict__ be1, const float* __restrict__ m1,
    const float* __restrict__ v1, const float* __restrict__ W1b,
    const float* __restrict__ b1b, unsigned short* __restrict__ h1b, int N) {
    __shared__ float w1b[1024];
    __shared__ float t1s[64][33];
    int t = threadIdx.x;
    for (int i = t; i < 1024; i += 256) w1b[i] = W1b[i];
    __syncthreads();                    // weights visible BEFORE variable gather
    int g = t >> 2, l = t & 3;
    int node = blockIdx.x * 64 + g;
    int c0 = l << 3;
    bool act = node < N;
    float acc[8] = {0.f, 0.f, 0.f, 0.f, 0.f, 0.f, 0.f, 0.f};
    if (act) {
        int2 se = row_se[node];
        uint4 sv = *(const uint4*)&y1b[(size_t)node * 32 + c0];   // hoisted self load
        gather_seg8(y1b, epack, se.x, se.y, c0, acc);
        gacc8(sv, 1.f, acc);                        // + self
        #pragma unroll
        for (int j = 0; j < 8; ++j) {
            int c = c0 + j;
            float scale = g1[c] * rsqrtf(v1[c] + BN_EPS);
            t1s[g][c] = fmaxf((acc[j] + b1a[c] - m1[c]) * scale + be1[c], 0.f);
        }
    }
    asm volatile("" ::: "memory");      // same-wave LDS producer/consumer: no barrier
    if (act) {
        float a[8];
        #pragma unroll
        for (int j = 0; j < 8; ++j) a[j] = b1b[c0 + j];
        #pragma unroll
        for (int k = 0; k < 32; ++k) {
            float tv = t1s[g][k];
            const float* wr = &w1b[k * 32 + c0];
            #pragma unroll
            for (int j = 0; j < 8; ++j) a[j] += tv * wr[j];
        }
        unsigned long long p0 = 0, p1 = 0;
        #pragma unroll
        for (int j = 0; j < 4; ++j)
            p0 |= (unsigned long long)f2bf(fmaxf(a[j], 0.f)) << (16 * j);
        #pragma unroll
        for (int j = 0; j < 4; ++j)
            p1 |= (unsigned long long)f2bf(fmaxf(a[4 + j], 0.f)) << (16 * j);
        __builtin_nontemporal_store(p0, (unsigned long long*)&h1b[(size_t)node * 32 + c0 + 0]);
        __builtin_nontemporal_store(p1, (unsigned long long*)&h1b[(size_t)node * 32 + c0 + 4]);
    }
}

// ------- K4: gather(h1b) -> s1 ; @W2a + BN + ReLU -> t2b  (64 nodes/block) -------
__global__ __launch_bounds__(256) void layer2a_kernel(
    const unsigned short* __restrict__ h1b, const int2* __restrict__ row_se,
    const int2* __restrict__ epack,
    const float* __restrict__ W2a, const float* __restrict__ b2a,
    const float* __restrict__ g2, const float* __restrict__ be2,
    const float* __restrict__ m2, const float* __restrict__ v2,
    unsigned short* __restrict__ t2b, int N) {
    __shared__ float w2a[2048];
    __shared__ float s1s[64][33];
    __shared__ float sc2s[64], sh2s[64];
    int t = threadIdx.x;
    for (int i = t; i < 2048; i += 256) w2a[i] = W2a[i];
    if (t < 64) {
        float sc = g2[t] * rsqrtf(v2[t] + BN_EPS);
        sc2s[t] = sc;
        sh2s[t] = (b2a[t] - m2[t]) * sc + be2[t];   // b2a folded into BN shift
    }
    __syncthreads();                    // weights visible BEFORE variable gather
    int g = t >> 2, l = t & 3;
    int node = blockIdx.x * 64 + g;
    int c0 = l << 3;
    bool act = node < N;
    float acc[8] = {0.f, 0.f, 0.f, 0.f, 0.f, 0.f, 0.f, 0.f};
    if (act) {
        int2 se = row_se[node];
        uint4 sv = *(const uint4*)&h1b[(size_t)node * 32 + c0];   // hoisted self load
        gather_seg8(h1b, epack, se.x, se.y, c0, acc);
        gacc8(sv, 1.f, acc);
        #pragma unroll
        for (int j = 0; j < 8; ++j) s1s[g][c0 + j] = acc[j];
    }
    asm volatile("" ::: "memory");      // same-wave LDS producer/consumer
    if (act) {
        int d0 = l << 4;                 // 16 output cols per lane
        float a[16];
        #pragma unroll
        for (int j = 0; j < 16; ++j) a[j] = 0.f;
        #pragma unroll
        for (int k = 0; k < 32; ++k) {
            float sv = s1s[g][k];
            const float* wr = &w2a[k * 64 + d0];
            #pragma unroll
            for (int j = 0; j < 16; ++j) a[j] += sv * wr[j];
        }
        unsigned long long pk[4] = {0, 0, 0, 0};
        #pragma unroll
        for (int j = 0; j < 16; ++j) {
            int c = d0 + j;
            float o = fmaxf(a[j] * sc2s[c] + sh2s[c], 0.f);
            pk[j >> 2] |= (unsigned long long)f2bf(o) << (16 * (j & 3));
        }
        #pragma unroll
        for (int q = 0; q < 4; ++q)
            __builtin_nontemporal_store(pk[q],
                (unsigned long long*)&t2b[(size_t)node * 64 + d0 + 4 * q]);
    }
}

// ------- K5: out = t2b@W2b + b2b  (32 nodes/block, 8 thr/node, 8 outs/thread) -------
__global__ __launch_bounds__(256) void final_kernel(const unsigned short* __restrict__ t2b,
                                                    const float* __restrict__ W2b,
                                                    const float* __restrict__ b2b,
                                                    float* __restrict__ out, int N) {
    __shared__ float w2b[4096];        // 16 KB
    __shared__ float t2s[32][68];
    int t = threadIdx.x;
    for (int i = t; i < 4096; i += 256) w2b[i] = W2b[i];
    int g = t >> 3, l = t & 7;
    int node = blockIdx.x * 32 + g;
    int c0 = l << 3;
    bool act = node < N;
    if (act) {
        uint4 v = *(const uint4*)&t2b[(size_t)node * 64 + c0];
        t2s[g][c0 + 0] = bflo(v.x); t2s[g][c0 + 1] = bfhi(v.x);
        t2s[g][c0 + 2] = bflo(v.y); t2s[g][c0 + 3] = bfhi(v.y);
        t2s[g][c0 + 4] = bflo(v.z); t2s[g][c0 + 5] = bfhi(v.z);
        t2s[g][c0 + 6] = bflo(v.w); t2s[g][c0 + 7] = bfhi(v.w);
    }
    __syncthreads();
    if (act) {
        float a[8];
        #pragma unroll
        for (int j = 0; j < 8; ++j) a[j] = b2b[c0 + j];
        #pragma unroll 8
        for (int k = 0; k < 64; ++k) {
            float tv = t2s[g][k];
            const float* wr = &w2b[k * 64 + c0];
            float4 w0 = *(const float4*)wr;
            float4 w1 = *(const float4*)(wr + 4);
            a[0] += tv * w0.x; a[1] += tv * w0.y; a[2] += tv * w0.z; a[3] += tv * w0.w;
            a[4] += tv * w1.x; a[5] += tv * w1.y; a[6] += tv * w1.z; a[7] += tv * w1.w;
        }
        *(float4*)&out[(size_t)node * 64 + c0 + 0] = *(float4*)&a[0];
        *(float4*)&out[(size_t)node * 64 + c0 + 4] = *(float4*)&a[4];
    }
}

extern "C" void kernel_launch(void* const* d_in, const int* in_sizes, int n_in,
                              void* d_out, int out_size, void* d_ws, size_t ws_size,
                              hipStream_t stream) {
    const float* x   = (const float*)d_in[0];
    const float* ew  = (const float*)d_in[1];
    const float* W1a = (const float*)d_in[2];
    const float* b1a = (const float*)d_in[3];
    const float* g1  = (const float*)d_in[4];
    const float* be1 = (const float*)d_in[5];
    const float* m1  = (const float*)d_in[6];
    const float* v1  = (const float*)d_in[7];
    const float* W1b = (const float*)d_in[8];
    const float* b1b = (const float*)d_in[9];
    const float* W2a = (const float*)d_in[10];
    const float* b2a = (const float*)d_in[11];
    const float* g2  = (const float*)d_in[12];
    const float* be2 = (const float*)d_in[13];
    const float* m2  = (const float*)d_in[14];
    const float* v2  = (const float*)d_in[15];
    const float* W2b = (const float*)d_in[16];
    const float* b2b = (const float*)d_in[17];
    const int*   ei  = (const int*)d_in[18];

    const int N = in_sizes[0] / 128;
    const int E = in_sizes[1];
    const int NBUCK = (N + BKT - 1) >> BKT_SH;   // 782 for N=100000 (<= MAXB)
    const int NCUR  = NBUCK * 16;
    const int G_STAGE = (E + EPB - 1) / EPB;     // 391
    const int G_GEMM  = (N + 127) / 128;         // 782

    // ws layout: y1b | row_se | gcur | epack | staged
    // h1b aliases staged[0..N*32); t2b aliases staged[N*32..) — staged dead
    // after refill; h1b reads and t2b writes are disjoint ranges.
    unsigned short* y1b = (unsigned short*)d_ws;              // N*32 bf16
    int2*  row_se  = (int2*)(y1b + (size_t)N * 32);           // N int2
    int*   gcur    = (int*)(row_se + N);                      // NCUR (64B pad)
    int2*  epack   = (int2*)(gcur + NCUR + 16);               // NBUCK*cap
    size_t fixed_bytes = (char*)epack - (char*)d_ws;
    size_t avail = (ws_size > fixed_bytes) ? (ws_size - fixed_bytes) : 0;
    int cap = (int)((avail / (2 * sizeof(int2))) / NBUCK);
    cap &= ~63;
    if (cap > LDS_E) cap = LDS_E;   // mean bucket load ~2048, max ~2300
    int2* staged = epack + (size_t)NBUCK * cap;
    unsigned short* h1b = (unsigned short*)staged;            // N*32 bf16 (alias)
    unsigned short* t2b = h1b + (size_t)N * 32;               // N*64 bf16 (alias)

    hipMemsetAsync(gcur, 0, (size_t)NCUR * sizeof(int), stream);
    gs_kernel<<<G_STAGE + G_GEMM, 512, 0, stream>>>(x, W1a, y1b, ei, ew, gcur, staged,
                                                    N, E, cap, NBUCK, G_STAGE);
    refill_kernel<<<NBUCK, 256, 0, stream>>>(staged, gcur, epack, row_se, N, cap);
    layer1_kernel<<<(N + 63) / 64, 256, 0, stream>>>(y1b, row_se, epack,
                                                     b1a, g1, be1, m1, v1, W1b, b1b, h1b, N);
    layer2a_kernel<<<(N + 63) / 64, 256, 0, stream>>>(h1b, row_se, epack,
                                                      W2a, b2a, g2, be2, m2, v2, t2b, N);
    final_kernel<<<(N + 31) / 32, 256, 0, stream>>>(t2b, W2b, b2b, (float*)d_out, N);
}